// Round 1
// baseline (1562.542 us; speedup 1.0000x reference)
//
#include <hip/hip_runtime.h>
#include <stdint.h>

#define NN 50000
#define NE 800000
#define DN 64
#define DEIN 192
#define DM 128
#define CAP 64          // bucket capacity per node (Poisson(16); P(>=64) ~ 1e-18)
#define EB 64           // edges per tile in edge kernel
#define SA_STRIDE 200   // 192 + 8 pad (bf16) -> row stride 400B, breaks bank conflicts
#define SB_STRIDE 200
#define SO_STRIDE 136   // 128 + 8 pad

typedef __attribute__((ext_vector_type(4))) float f32x4;
typedef __attribute__((ext_vector_type(8))) short s16x8;

__device__ __forceinline__ unsigned short f2bf(float f) {
  union { float f; uint32_t u; } v; v.f = f;
  uint32_t u = v.u;
  u += 0x7FFF + ((u >> 16) & 1);   // RNE
  return (unsigned short)(u >> 16);
}
__device__ __forceinline__ float bf2f(unsigned short h) {
  union { uint32_t u; float f; } v; v.u = ((uint32_t)h) << 16;
  return v.f;
}

// ---- prep: transpose W1 (both dirs) to [n][k] bf16; fold the column-swap of
// edge_in_r into W1_r's rows so both directions share the same A tiles.
__global__ void kw(const float* __restrict__ W1f, const float* __restrict__ W1r,
                   unsigned short* __restrict__ B1fT, unsigned short* __restrict__ B1rT) {
  int i = blockIdx.x * 256 + threadIdx.x;
  if (i >= DM * DEIN) return;
  int n = i / DEIN, k = i % DEIN;
  int pk = k < 64 ? k + 64 : (k < 128 ? k - 64 : k);
  B1fT[i] = f2bf(W1f[k * DM + n]);
  B1rT[i] = f2bf(W1r[pk * DM + n]);
}

// ---- bucket build: per-node incoming(to) / outgoing(from) edge lists
__global__ void kbucket(const int* __restrict__ tidx, const int* __restrict__ fidx,
                        int* __restrict__ cnt_to, int* __restrict__ cnt_from,
                        int* __restrict__ b_to, int* __restrict__ b_from) {
  int e = blockIdx.x * 256 + threadIdx.x;
  if (e >= NE) return;
  int t = tidx[e]; int s = atomicAdd(&cnt_to[t], 1);   if (s  < CAP) b_to[t * CAP + s]  = e;
  int f = fidx[e]; int s2 = atomicAdd(&cnt_from[f], 1); if (s2 < CAP) b_from[f * CAP + s2] = e;
}

// ---- edge kernel: h1 = relu([ns[from], ns[to], ef] @ B^T + b1) -> H (bf16)
// Same kernel for both directions (direction folded into BT).
__launch_bounds__(256, 2)
__global__ void kedge(const float* __restrict__ ns, const float* __restrict__ ef,
                      const int* __restrict__ fidx, const int* __restrict__ tidx,
                      const unsigned short* __restrict__ BT, const float* __restrict__ b1,
                      unsigned short* __restrict__ H, int e_base, int e_count) {
  __shared__ __align__(16) unsigned short sB[DM][SB_STRIDE];   // W^T bf16 [n][k]
  __shared__ __align__(16) unsigned short sA[EB][SA_STRIDE];   // edge_in bf16 [e][k]
  __shared__ float sb1[DM];
  int tid = threadIdx.x;
  int wid = tid >> 6, lane = tid & 63, g = lane >> 4, lr = lane & 15;

  // stage weights once per block (BT already bf16 + transposed in WS)
  for (int i = tid; i < DM * 24; i += 256) {
    int r = i / 24, c = i % 24;
    *(int4*)&sB[r][c * 8] = *(const int4*)&BT[r * DEIN + c * 8];
  }
  if (tid < DM) sb1[tid] = b1[tid];
  __syncthreads();

  int ntiles = (e_count + EB - 1) / EB;
  for (int tile = blockIdx.x; tile < ntiles; tile += gridDim.x) {
    int e0 = e_base + tile * EB;
    // stage A: 64 edges x 192 cols as bf16 (gather + convert), float4 units
    for (int i = tid; i < EB * 48; i += 256) {
      int el = i / 48, q = i % 48;
      int e = e0 + el;
      int ec = e < NE ? e : NE - 1;
      int seg = q >> 4, c4 = q & 15;
      const float* src;
      if (seg == 0)      src = ns + (size_t)fidx[ec] * DN + c4 * 4;
      else if (seg == 1) src = ns + (size_t)tidx[ec] * DN + c4 * 4;
      else               src = ef + (size_t)ec * DN + c4 * 4;
      float4 v = (e < e_base + e_count) ? *(const float4*)src : float4{0.f, 0.f, 0.f, 0.f};
      ushort4 b; b.x = f2bf(v.x); b.y = f2bf(v.y); b.z = f2bf(v.z); b.w = f2bf(v.w);
      *(ushort4*)&sA[el][seg * 64 + c4 * 4] = b;
    }
    __syncthreads();

    // MFMA: wave wid owns rows [wid*16, wid*16+16), all 8 N-tiles
    f32x4 acc[8];
#pragma unroll
    for (int nt = 0; nt < 8; nt++) acc[nt] = f32x4{0.f, 0.f, 0.f, 0.f};
#pragma unroll
    for (int kt = 0; kt < 6; kt++) {
      s16x8 a = *(const s16x8*)&sA[wid * 16 + lr][kt * 32 + g * 8];
#pragma unroll
      for (int nt = 0; nt < 8; nt++) {
        s16x8 b = *(const s16x8*)&sB[nt * 16 + lr][kt * 32 + g * 8];
        acc[nt] = __builtin_amdgcn_mfma_f32_16x16x32_bf16(a, b, acc[nt], 0, 0, 0);
      }
    }
    __syncthreads();  // all waves done reading sA; reuse as output bounce

    unsigned short (*sO)[SO_STRIDE] = (unsigned short(*)[SO_STRIDE])&sA[0][0];
#pragma unroll
    for (int nt = 0; nt < 8; nt++) {
      int n = nt * 16 + lr;
      float bb = sb1[n];
#pragma unroll
      for (int r = 0; r < 4; r++) {
        float h = fmaxf(acc[nt][r] + bb, 0.f);
        sO[wid * 16 + 4 * g + r][n] = f2bf(h);
      }
    }
    __syncthreads();
    // coalesced H write: 64 rows x 256B
    for (int i = tid; i < EB * 16; i += 256) {
      int r = i / 16, c8 = i % 16;
      int e = e0 + r;
      if (e < e_base + e_count)
        *(int4*)&H[(size_t)(e - e_base) * DM + c8 * 8] = *(const int4*)&sO[r][c8 * 8];
    }
    __syncthreads();
  }
}

// ---- aggregation: per node, sum H rows listed in its bucket (atomic-free)
__global__ void kagg(const unsigned short* __restrict__ H, const int* __restrict__ bucket,
                     const int* __restrict__ cnt, float* __restrict__ aggH,
                     int e_base, int e_count) {
  int w = threadIdx.x >> 6, lane = threadIdx.x & 63;
  int n = blockIdx.x * 4 + w;
  if (n >= NN) return;
  int m = cnt[n]; if (m > CAP) m = CAP;
  const int* lst = bucket + (size_t)n * CAP;
  float s0 = 0.f, s1 = 0.f;
  for (int j = 0; j < m; j++) {
    int e = lst[j];
    if (e < e_base || e >= e_base + e_count) continue;
    uint32_t v = *(const uint32_t*)&H[(size_t)(e - e_base) * DM + lane * 2];
    s0 += bf2f((unsigned short)(v & 0xFFFF));
    s1 += bf2f((unsigned short)(v >> 16));
  }
  float* dst = aggH + (size_t)n * DM + lane * 2;
  if (e_base == 0) { dst[0] = s0; dst[1] = s1; }
  else             { dst[0] += s0; dst[1] += s1; }
}

// ---- per-node second layer: msg (+)= aggH @ W2 + cnt * b2
__launch_bounds__(256, 2)
__global__ void kmm(const float* __restrict__ aggH, const float* __restrict__ W2,
                    const float* __restrict__ b2, const int* __restrict__ cnt,
                    float* __restrict__ msg, int beta) {
  __shared__ unsigned short sW[DM][DM];
  __shared__ float sb[DM];
  __shared__ float sx[4][DM];
  int tid = threadIdx.x;
  for (int i = tid; i < DM * DM; i += 256) sW[i / DM][i % DM] = f2bf(W2[i]);
  if (tid < DM) sb[tid] = b2[tid];
  __syncthreads();
  int w = tid >> 6, lane = tid & 63;
  int ngroups = (NN + 3) / 4;
  for (int grp = blockIdx.x; grp < ngroups; grp += gridDim.x) {
    int n = grp * 4 + w;
    bool valid = n < NN;
    float2 v = valid ? *(const float2*)&aggH[(size_t)n * DM + lane * 2] : float2{0.f, 0.f};
    *(float2*)&sx[w][lane * 2] = v;
    float a0 = 0.f, a1 = 0.f;
#pragma unroll 4
    for (int k = 0; k < DM; k++) {
      float x = sx[w][k];
      a0 += x * bf2f(sW[k][lane]);
      a1 += x * bf2f(sW[k][lane + 64]);
    }
    if (valid) {
      float c = (float)cnt[n];
      float r0 = a0 + c * sb[lane], r1 = a1 + c * sb[lane + 64];
      float* dst = &msg[(size_t)n * DM];
      if (beta) { r0 += dst[lane]; r1 += dst[lane + 64]; }
      dst[lane] = r0; dst[lane + 64] = r1;
    }
  }
}

// ---- node MLP + residual: out = x + relu([msg, x] @ Wn1 + bn1) @ Wn2 + bn2
__launch_bounds__(256, 2)
__global__ void knode(const float* __restrict__ msg, const float* __restrict__ ns,
                      const float* __restrict__ Wn1, const float* __restrict__ bn1,
                      const float* __restrict__ Wn2, const float* __restrict__ bn2,
                      float* __restrict__ out) {
  __shared__ unsigned short sW1[DEIN][DM];
  __shared__ unsigned short sW2[DM][DN];
  __shared__ float sb1[DM], sb2[DN];
  __shared__ float sx[4][DEIN];
  __shared__ float sh[4][DM];
  int tid = threadIdx.x;
  for (int i = tid; i < DEIN * DM; i += 256) sW1[i / DM][i % DM] = f2bf(Wn1[i]);
  for (int i = tid; i < DM * DN; i += 256)  sW2[i / DN][i % DN] = f2bf(Wn2[i]);
  if (tid < DM) sb1[tid] = bn1[tid];
  if (tid < DN) sb2[tid] = bn2[tid];
  __syncthreads();
  int w = tid >> 6, lane = tid & 63;
  int ngroups = (NN + 3) / 4;
  for (int grp = blockIdx.x; grp < ngroups; grp += gridDim.x) {
    int n = grp * 4 + w;
    bool valid = n < NN;
    float2 mv = valid ? *(const float2*)&msg[(size_t)n * DM + lane * 2] : float2{0.f, 0.f};
    *(float2*)&sx[w][lane * 2] = mv;
    float xreg = valid ? ns[(size_t)n * DN + lane] : 0.f;
    sx[w][DM + lane] = xreg;
    float a0 = 0.f, a1 = 0.f;
#pragma unroll 4
    for (int k = 0; k < DEIN; k++) {
      float x = sx[w][k];
      a0 += x * bf2f(sW1[k][lane]);
      a1 += x * bf2f(sW1[k][lane + 64]);
    }
    sh[w][lane]      = fmaxf(a0 + sb1[lane], 0.f);
    sh[w][lane + 64] = fmaxf(a1 + sb1[lane + 64], 0.f);
    float o = 0.f;
#pragma unroll 4
    for (int k = 0; k < DM; k++) o += sh[w][k] * bf2f(sW2[k][lane]);
    if (valid) out[(size_t)n * DN + lane] = xreg + o + sb2[lane];
  }
}

extern "C" void kernel_launch(void* const* d_in, const int* in_sizes, int n_in,
                              void* d_out, int out_size, void* d_ws, size_t ws_size,
                              hipStream_t stream) {
  const float* ns  = (const float*)d_in[0];
  const float* ef  = (const float*)d_in[1];
  const float* W1f = (const float*)d_in[2];
  const float* b1f = (const float*)d_in[3];
  const float* W2f = (const float*)d_in[4];
  const float* b2f = (const float*)d_in[5];
  const float* W1r = (const float*)d_in[6];
  const float* b1r = (const float*)d_in[7];
  const float* W2r = (const float*)d_in[8];
  const float* b2r = (const float*)d_in[9];
  const float* Wn1 = (const float*)d_in[10];
  const float* bn1 = (const float*)d_in[11];
  const float* Wn2 = (const float*)d_in[12];
  const float* bn2 = (const float*)d_in[13];
  const int* fidx  = (const int*)d_in[14];
  const int* tidx  = (const int*)d_in[15];
  float* out = (float*)d_out;

  char* ws = (char*)d_ws;
  size_t off = 0;
  auto alloc = [&](size_t bytes) {
    off = (off + 255) & ~(size_t)255;
    void* p = ws + off; off += bytes; return p;
  };
  float* msg            = (float*)alloc((size_t)NN * DM * 4);
  float* aggH           = (float*)alloc((size_t)NN * DM * 4);
  int* b_to             = (int*)alloc((size_t)NN * CAP * 4);
  int* b_from           = (int*)alloc((size_t)NN * CAP * 4);
  int* cnt_to           = (int*)alloc((size_t)NN * 4);
  int* cnt_from         = (int*)alloc((size_t)NN * 4);
  unsigned short* B1fT  = (unsigned short*)alloc((size_t)DM * DEIN * 2);
  unsigned short* B1rT  = (unsigned short*)alloc((size_t)DM * DEIN * 2);
  off = (off + 255) & ~(size_t)255;
  size_t rem = ws_size > off ? ws_size - off : 0;
  size_t chunk_sz = rem / (DM * 2);
  int chunk = chunk_sz > (size_t)NE ? NE : (int)chunk_sz;
  if (chunk < EB) return;  // insufficient workspace: output stays zero (loud failure)
  unsigned short* H = (unsigned short*)alloc((size_t)chunk * DM * 2);

  hipMemsetAsync(cnt_to, 0, (size_t)NN * 4, stream);
  hipMemsetAsync(cnt_from, 0, (size_t)NN * 4, stream);
  kw<<<(DM * DEIN + 255) / 256, 256, 0, stream>>>(W1f, W1r, B1fT, B1rT);
  kbucket<<<(NE + 255) / 256, 256, 0, stream>>>(tidx, fidx, cnt_to, cnt_from, b_to, b_from);

  for (int dir = 0; dir < 2; dir++) {
    const unsigned short* BT = dir == 0 ? B1fT : B1rT;
    const float* b1 = dir == 0 ? b1f : b1r;
    const float* W2 = dir == 0 ? W2f : W2r;
    const float* b2 = dir == 0 ? b2f : b2r;
    const int* bucket = dir == 0 ? b_to : b_from;
    const int* cnt = dir == 0 ? cnt_to : cnt_from;
    for (int c0 = 0; c0 < NE; c0 += chunk) {
      int cc = (NE - c0) < chunk ? (NE - c0) : chunk;
      int ntiles = (cc + EB - 1) / EB;
      int grid = ntiles < 1024 ? ntiles : 1024;
      kedge<<<grid, 256, 0, stream>>>(ns, ef, fidx, tidx, BT, b1, H, c0, cc);
      kagg<<<(NN + 3) / 4, 256, 0, stream>>>(H, bucket, cnt, aggH, c0, cc);
    }
    kmm<<<1024, 256, 0, stream>>>(aggH, W2, b2, cnt, msg, dir);
  }
  knode<<<1024, 256, 0, stream>>>(msg, ns, Wn1, bn1, Wn2, bn2, out);
}

// Round 2
// 690.880 us; speedup vs baseline: 2.2617x; 2.2617x over previous
//
#include <hip/hip_runtime.h>
#include <stdint.h>

#define NN 50000
#define NE 800000
#define DN 64
#define DEIN 192
#define DM 128
#define CAP 64          // bucket capacity (Poisson(16); P(>=64) negligible)
#define EB 64           // edge/node rows per tile

#define SA_STR 216      // 432B row stride: 16B-aligned, 2-way bank alias (free)
#define SO_STR 136      // 272B: 16B-aligned
#define SX_STR 264      // 528B: 16B-aligned, 2-way alias

typedef __attribute__((ext_vector_type(4))) float f32x4;
typedef __attribute__((ext_vector_type(8))) short s16x8;

__device__ __forceinline__ unsigned short f2bf(float f) {
  union { float f; uint32_t u; } v; v.f = f;
  uint32_t u = v.u;
  u += 0x7FFF + ((u >> 16) & 1);   // RNE
  return (unsigned short)(u >> 16);
}
__device__ __forceinline__ float bf2f(unsigned short h) {
  union { uint32_t u; float f; } v; v.u = ((uint32_t)h) << 16;
  return v.f;
}
__device__ __forceinline__ ushort4 cvt4(float4 v) {
  ushort4 b; b.x = f2bf(v.x); b.y = f2bf(v.y); b.z = f2bf(v.z); b.w = f2bf(v.w);
  return b;
}

// ---- weight prep: bf16 transposed [n][k] layouts; reverse direction's
// column-swap folded into B1rT rows; W2f/W2r stacked into one K=256 matrix.
__global__ void kw2(const float* __restrict__ W1f, const float* __restrict__ W1r,
                    const float* __restrict__ W2f, const float* __restrict__ W2r,
                    const float* __restrict__ Wn1, const float* __restrict__ Wn2,
                    unsigned short* __restrict__ B1fT, unsigned short* __restrict__ B1rT,
                    unsigned short* __restrict__ B2T, unsigned short* __restrict__ Bn1T,
                    unsigned short* __restrict__ Bn2T) {
  int i = blockIdx.x * 256 + threadIdx.x;
  if (i < DM * DEIN) {
    int n = i / DEIN, k = i % DEIN;
    int pk = k < 64 ? k + 64 : (k < 128 ? k - 64 : k);
    B1fT[i] = f2bf(W1f[k * DM + n]);
    B1rT[i] = f2bf(W1r[pk * DM + n]);
    Bn1T[i] = f2bf(Wn1[k * DM + n]);
  }
  if (i < DM * 256) {
    int n = i / 256, k = i % 256;
    B2T[i] = f2bf(k < DM ? W2f[k * DM + n] : W2r[(k - DM) * DM + n]);
  }
  if (i < DN * DM) {
    int n = i / DM, k = i % DM;
    Bn2T[i] = f2bf(Wn2[k * DN + n]);
  }
}

// ---- bucket build
__global__ void kbucket(const int* __restrict__ tidx, const int* __restrict__ fidx,
                        int* __restrict__ cnt_to, int* __restrict__ cnt_from,
                        int* __restrict__ b_to, int* __restrict__ b_from) {
  int e = blockIdx.x * 256 + threadIdx.x;
  if (e >= NE) return;
  int t = tidx[e]; int s = atomicAdd(&cnt_to[t], 1);    if (s  < CAP) b_to[t * CAP + s]   = e;
  int f = fidx[e]; int s2 = atomicAdd(&cnt_from[f], 1); if (s2 < CAP) b_from[f * CAP + s2] = e;
}

// ---- fused edge kernel: both directions per staged tile.
// 1024 threads = 16 waves; wave = (dir = w>>3, nt = w&7); B frags in regs.
// Double-buffered sA, T14 split staging (issue loads -> MFMA -> cvt+ds_write).
__launch_bounds__(1024, 4)
__global__ void kedge2(const float* __restrict__ ns, const float* __restrict__ ef,
                       const int* __restrict__ fidx, const int* __restrict__ tidx,
                       const unsigned short* __restrict__ B1fT,
                       const unsigned short* __restrict__ B1rT,
                       const float* __restrict__ b1f, const float* __restrict__ b1r,
                       unsigned short* __restrict__ Hf, unsigned short* __restrict__ Hr,
                       int e_base, int e_count) {
  __shared__ __align__(16) unsigned short sA[2][EB][SA_STR];
  __shared__ __align__(16) unsigned short sO[2][EB][SO_STR];
  __shared__ float sb[2][DM];
  const int tid = threadIdx.x;
  const int w = tid >> 6, lane = tid & 63, g = lane >> 4, lr = lane & 15;
  const int dir = w >> 3, nt = w & 7;

  if (tid < 2 * DM) sb[tid >> 7][tid & 127] = (tid < DM ? b1f[tid] : b1r[tid - DM]);

  const unsigned short* BT = dir ? B1rT : B1fT;
  s16x8 bq[6];
#pragma unroll
  for (int kt = 0; kt < 6; kt++)
    bq[kt] = *(const s16x8*)&BT[(nt * 16 + lr) * DEIN + kt * 32 + g * 8];

  const int srow = tid >> 4, c4 = tid & 15;   // 16 threads per edge row
  const int ntiles = (e_count + EB - 1) / EB;

  float4 sv0, sv1, sv2;
  auto issue = [&](int tile) {
    int ei = tile * EB + srow;
    bool val = ei < e_count;
    int ec = val ? (e_base + ei) : e_base;
    int f = fidx[ec], t = tidx[ec];
    float4 z = {0.f, 0.f, 0.f, 0.f};
    sv0 = val ? *((const float4*)(ns + (size_t)f * DN) + c4) : z;
    sv1 = val ? *((const float4*)(ns + (size_t)t * DN) + c4) : z;
    sv2 = val ? *((const float4*)(ef + (size_t)ec * DN) + c4) : z;
  };
  auto store = [&](int buf) {
    *(ushort4*)&sA[buf][srow][0   + c4 * 4] = cvt4(sv0);
    *(ushort4*)&sA[buf][srow][64  + c4 * 4] = cvt4(sv1);
    *(ushort4*)&sA[buf][srow][128 + c4 * 4] = cvt4(sv2);
  };

  int cur = 0;
  issue(blockIdx.x);
  store(0);
  __syncthreads();
  for (int t = blockIdx.x; t < ntiles; t += gridDim.x) {
    int tn = t + (int)gridDim.x;
    bool hn = tn < ntiles;
    if (hn) issue(tn);                       // loads in flight during MFMA
    f32x4 acc[4];
#pragma unroll
    for (int m = 0; m < 4; m++) {
      s16x8 a[6];
#pragma unroll
      for (int kt = 0; kt < 6; kt++)
        a[kt] = *(const s16x8*)&sA[cur][m * 16 + lr][kt * 32 + g * 8];
      f32x4 c = {0.f, 0.f, 0.f, 0.f};
#pragma unroll
      for (int kt = 0; kt < 6; kt++)
        c = __builtin_amdgcn_mfma_f32_16x16x32_bf16(a[kt], bq[kt], c, 0, 0, 0);
      acc[m] = c;
    }
    if (hn) store(cur ^ 1);
    __syncthreads();
    // epilogue: relu+bias -> sO[dir] (bf16)
    float bb = sb[dir][nt * 16 + lr];
#pragma unroll
    for (int m = 0; m < 4; m++)
#pragma unroll
      for (int r = 0; r < 4; r++)
        sO[dir][m * 16 + g * 4 + r][nt * 16 + lr] = f2bf(fmaxf(acc[m][r] + bb, 0.f));
    __syncthreads();
    // coalesced copy-out of both H buffers
#pragma unroll
    for (int h = 0; h < 2; h++) {
      int c = tid + h * 1024;
      int d = c >> 10, rem = c & 1023, rr = rem >> 4, c8 = rem & 15;
      int ei = t * EB + rr;
      if (ei < e_count) {
        unsigned short* H = d ? Hr : Hf;
        *(int4*)&H[(size_t)ei * DM + c8 * 8] = *(const int4*)&sO[d][rr][c8 * 8];
      }
    }
    cur ^= 1;
  }
}

// ---- aggregation, both directions, into agg[NN][256] (F | R), f32
__global__ void kagg2(const unsigned short* __restrict__ Hf, const unsigned short* __restrict__ Hr,
                      const int* __restrict__ b_to, const int* __restrict__ b_from,
                      const int* __restrict__ cnt_to, const int* __restrict__ cnt_from,
                      float* __restrict__ agg, int e_base, int e_count) {
  int w = threadIdx.x >> 6, lane = threadIdx.x & 63;
  int n = blockIdx.x * 4 + w;
  if (n >= NN) return;
#pragma unroll
  for (int d = 0; d < 2; d++) {
    const unsigned short* H = d ? Hr : Hf;
    const int* bkt = (d ? b_from : b_to) + (size_t)n * CAP;
    int m = d ? cnt_from[n] : cnt_to[n]; if (m > CAP) m = CAP;
    float s0 = 0.f, s1 = 0.f;
    for (int j = 0; j < m; j++) {
      int e = bkt[j] - e_base;
      if (e < 0 || e >= e_count) continue;
      uint32_t v = *(const uint32_t*)&H[(size_t)e * DM + lane * 2];
      s0 += bf2f((unsigned short)(v & 0xFFFF));
      s1 += bf2f((unsigned short)(v >> 16));
    }
    float* dst = agg + (size_t)n * 256 + d * DM + lane * 2;
    if (e_base == 0) { dst[0] = s0; dst[1] = s1; }
    else             { dst[0] += s0; dst[1] += s1; }
  }
}

// ---- second layer as MFMA GEMM: msg = [aggF|aggR] @ [W2f;W2r] + cntT*b2f + cntF*b2r
__launch_bounds__(256, 2)
__global__ void kmm3(const float* __restrict__ agg, const unsigned short* __restrict__ B2T,
                     const float* __restrict__ b2f, const float* __restrict__ b2r,
                     const int* __restrict__ cnt_to, const int* __restrict__ cnt_from,
                     unsigned short* __restrict__ msg) {
  __shared__ __align__(16) unsigned short sX[2][EB][SX_STR];
  __shared__ float sb[2][DM];
  const int tid = threadIdx.x;
  const int w = tid >> 6, lane = tid & 63, g = lane >> 4, lr = lane & 15;
  if (tid < 2 * DM) sb[tid >> 7][tid & 127] = tid < DM ? b2f[tid] : b2r[tid - DM];

  s16x8 bq[2][8];
#pragma unroll
  for (int p = 0; p < 2; p++)
#pragma unroll
    for (int kt = 0; kt < 8; kt++)
      bq[p][kt] = *(const s16x8*)&B2T[((2 * w + p) * 16 + lr) * 256 + kt * 32 + g * 8];

  const int ntiles = (NN + EB - 1) / EB;
  auto stage = [&](int buf, int tile) {
    for (int i = tid; i < EB * 64; i += 256) {
      int rr = i >> 6, q = i & 63;
      int node = tile * EB + rr; if (node >= NN) node = NN - 1;
      float4 v = *((const float4*)(agg + (size_t)node * 256) + q);
      *(ushort4*)&sX[buf][rr][q * 4] = cvt4(v);
    }
  };
  int cur = 0;
  stage(0, blockIdx.x);
  __syncthreads();
  for (int t = blockIdx.x; t < ntiles; t += gridDim.x) {
    int tn = t + (int)gridDim.x;
    bool hn = tn < ntiles;
    if (hn) stage(cur ^ 1, tn);
    f32x4 acc[4][2];
#pragma unroll
    for (int m = 0; m < 4; m++) {
      s16x8 a[8];
#pragma unroll
      for (int kt = 0; kt < 8; kt++)
        a[kt] = *(const s16x8*)&sX[cur][m * 16 + lr][kt * 32 + g * 8];
#pragma unroll
      for (int p = 0; p < 2; p++) {
        f32x4 c = {0.f, 0.f, 0.f, 0.f};
#pragma unroll
        for (int kt = 0; kt < 8; kt++)
          c = __builtin_amdgcn_mfma_f32_16x16x32_bf16(a[kt], bq[p][kt], c, 0, 0, 0);
        acc[m][p] = c;
      }
    }
    // epilogue (no LDS hazard: writes global only)
#pragma unroll
    for (int m = 0; m < 4; m++)
#pragma unroll
      for (int r = 0; r < 4; r++) {
        int node = t * EB + m * 16 + g * 4 + r;
        if (node < NN) {
          float cT = (float)cnt_to[node], cF = (float)cnt_from[node];
#pragma unroll
          for (int p = 0; p < 2; p++) {
            int cc = (2 * w + p) * 16 + lr;
            msg[(size_t)node * DM + cc] = f2bf(acc[m][p][r] + cT * sb[0][cc] + cF * sb[1][cc]);
          }
        }
      }
    __syncthreads();
    cur ^= 1;
  }
}

// ---- node MLP (two layers fused, MFMA) + residual
__launch_bounds__(256, 2)
__global__ void knode3(const unsigned short* __restrict__ msg, const float* __restrict__ ns,
                       const unsigned short* __restrict__ Bn1T, const unsigned short* __restrict__ Bn2T,
                       const float* __restrict__ bn1, const float* __restrict__ bn2,
                       float* __restrict__ out) {
  __shared__ __align__(16) unsigned short sX[2][EB][SA_STR];
  __shared__ __align__(16) unsigned short sH[EB][SO_STR];
  __shared__ float sb1[DM], sb2[DN];
  const int tid = threadIdx.x;
  const int w = tid >> 6, lane = tid & 63, g = lane >> 4, lr = lane & 15;
  if (tid < DM) sb1[tid] = bn1[tid];
  if (tid < DN) sb2[tid] = bn2[tid];

  s16x8 b1q[2][6], b2q[4];
#pragma unroll
  for (int p = 0; p < 2; p++)
#pragma unroll
    for (int kt = 0; kt < 6; kt++)
      b1q[p][kt] = *(const s16x8*)&Bn1T[((2 * w + p) * 16 + lr) * DEIN + kt * 32 + g * 8];
#pragma unroll
  for (int kt = 0; kt < 4; kt++)
    b2q[kt] = *(const s16x8*)&Bn2T[(w * 16 + lr) * DM + kt * 32 + g * 8];

  const int ntiles = (NN + EB - 1) / EB;
  auto stage = [&](int buf, int tile) {
    for (int i = tid; i < EB * 16; i += 256) {          // msg (bf16 direct copy)
      int rr = i >> 4, c8 = i & 15;
      int node = tile * EB + rr; if (node >= NN) node = NN - 1;
      *(int4*)&sX[buf][rr][c8 * 8] = *(const int4*)&msg[(size_t)node * DM + c8 * 8];
    }
    for (int i = tid; i < EB * 16; i += 256) {          // ns (f32 -> bf16)
      int rr = i >> 4, c4 = i & 15;
      int node = tile * EB + rr; if (node >= NN) node = NN - 1;
      float4 v = *((const float4*)(ns + (size_t)node * DN) + c4);
      *(ushort4*)&sX[buf][rr][DM + c4 * 4] = cvt4(v);
    }
  };
  int cur = 0;
  stage(0, blockIdx.x);
  __syncthreads();
  for (int t = blockIdx.x; t < ntiles; t += gridDim.x) {
    int tn = t + (int)gridDim.x;
    bool hn = tn < ntiles;
    if (hn) stage(cur ^ 1, tn);
    f32x4 acc1[4][2];
#pragma unroll
    for (int m = 0; m < 4; m++) {
      s16x8 a[6];
#pragma unroll
      for (int kt = 0; kt < 6; kt++)
        a[kt] = *(const s16x8*)&sX[cur][m * 16 + lr][kt * 32 + g * 8];
#pragma unroll
      for (int p = 0; p < 2; p++) {
        f32x4 c = {0.f, 0.f, 0.f, 0.f};
#pragma unroll
        for (int kt = 0; kt < 6; kt++)
          c = __builtin_amdgcn_mfma_f32_16x16x32_bf16(a[kt], b1q[p][kt], c, 0, 0, 0);
        acc1[m][p] = c;
      }
    }
    __syncthreads();
#pragma unroll
    for (int m = 0; m < 4; m++)
#pragma unroll
      for (int p = 0; p < 2; p++) {
        int cc = (2 * w + p) * 16 + lr;
#pragma unroll
        for (int r = 0; r < 4; r++)
          sH[m * 16 + g * 4 + r][cc] = f2bf(fmaxf(acc1[m][p][r] + sb1[cc], 0.f));
      }
    __syncthreads();
#pragma unroll
    for (int m = 0; m < 4; m++) {
      s16x8 a2[4];
#pragma unroll
      for (int kt = 0; kt < 4; kt++)
        a2[kt] = *(const s16x8*)&sH[m * 16 + lr][kt * 32 + g * 8];
      f32x4 c = {0.f, 0.f, 0.f, 0.f};
#pragma unroll
      for (int kt = 0; kt < 4; kt++)
        c = __builtin_amdgcn_mfma_f32_16x16x32_bf16(a2[kt], b2q[kt], c, 0, 0, 0);
      int col = w * 16 + lr;
#pragma unroll
      for (int r = 0; r < 4; r++) {
        int node = t * EB + m * 16 + g * 4 + r;
        if (node < NN)
          out[(size_t)node * DN + col] = ns[(size_t)node * DN + col] + c[r] + sb2[col];
      }
    }
    __syncthreads();
    cur ^= 1;
  }
}

extern "C" void kernel_launch(void* const* d_in, const int* in_sizes, int n_in,
                              void* d_out, int out_size, void* d_ws, size_t ws_size,
                              hipStream_t stream) {
  const float* ns  = (const float*)d_in[0];
  const float* ef  = (const float*)d_in[1];
  const float* W1f = (const float*)d_in[2];
  const float* b1f = (const float*)d_in[3];
  const float* W2f = (const float*)d_in[4];
  const float* b2f = (const float*)d_in[5];
  const float* W1r = (const float*)d_in[6];
  const float* b1r = (const float*)d_in[7];
  const float* W2r = (const float*)d_in[8];
  const float* b2r = (const float*)d_in[9];
  const float* Wn1 = (const float*)d_in[10];
  const float* bn1 = (const float*)d_in[11];
  const float* Wn2 = (const float*)d_in[12];
  const float* bn2 = (const float*)d_in[13];
  const int* fidx  = (const int*)d_in[14];
  const int* tidx  = (const int*)d_in[15];
  float* out = (float*)d_out;

  char* ws = (char*)d_ws;
  size_t off = 0;
  auto alloc = [&](size_t bytes) {
    off = (off + 255) & ~(size_t)255;
    void* p = ws + off; off += bytes; return p;
  };
  float* agg            = (float*)alloc((size_t)NN * 256 * 4);
  unsigned short* msg   = (unsigned short*)alloc((size_t)NN * DM * 2);
  int* b_to             = (int*)alloc((size_t)NN * CAP * 4);
  int* b_from           = (int*)alloc((size_t)NN * CAP * 4);
  int* cnt_to           = (int*)alloc((size_t)NN * 4);
  int* cnt_from         = (int*)alloc((size_t)NN * 4);
  unsigned short* B1fT  = (unsigned short*)alloc((size_t)DM * DEIN * 2);
  unsigned short* B1rT  = (unsigned short*)alloc((size_t)DM * DEIN * 2);
  unsigned short* B2T   = (unsigned short*)alloc((size_t)DM * 256 * 2);
  unsigned short* Bn1T  = (unsigned short*)alloc((size_t)DM * DEIN * 2);
  unsigned short* Bn2T  = (unsigned short*)alloc((size_t)DN * DM * 2);
  off = (off + 255) & ~(size_t)255;
  size_t rem = ws_size > off ? ws_size - off : 0;
  size_t chunk_sz = rem / (DM * 2 * 2);     // Hf + Hr per edge
  int chunk = chunk_sz > (size_t)NE ? NE : (int)chunk_sz;
  chunk &= ~(EB - 1);
  if (chunk < EB) return;
  unsigned short* Hf = (unsigned short*)alloc((size_t)chunk * DM * 2);
  unsigned short* Hr = (unsigned short*)alloc((size_t)chunk * DM * 2);

  hipMemsetAsync(cnt_to, 0, (size_t)NN * 4, stream);
  hipMemsetAsync(cnt_from, 0, (size_t)NN * 4, stream);
  kw2<<<128, 256, 0, stream>>>(W1f, W1r, W2f, W2r, Wn1, Wn2, B1fT, B1rT, B2T, Bn1T, Bn2T);
  kbucket<<<(NE + 255) / 256, 256, 0, stream>>>(tidx, fidx, cnt_to, cnt_from, b_to, b_from);

  for (int c0 = 0; c0 < NE; c0 += chunk) {
    int cc = (NE - c0) < chunk ? (NE - c0) : chunk;
    int ntiles = (cc + EB - 1) / EB;
    int grid = ntiles < 512 ? ntiles : 512;
    kedge2<<<grid, 1024, 0, stream>>>(ns, ef, fidx, tidx, B1fT, B1rT, b1f, b1r, Hf, Hr, c0, cc);
    kagg2<<<(NN + 3) / 4, 256, 0, stream>>>(Hf, Hr, b_to, b_from, cnt_to, cnt_from, agg, c0, cc);
  }
  int ntiles_n = (NN + EB - 1) / EB;
  int gridn = ntiles_n < 512 ? ntiles_n : 512;
  kmm3<<<gridn, 256, 0, stream>>>(agg, B2T, b2f, b2r, cnt_to, cnt_from, msg);
  knode3<<<gridn, 256, 0, stream>>>(msg, ns, Bn1T, Bn2T, bn1, bn2, out);
}

// Round 3
// 538.499 us; speedup vs baseline: 2.9017x; 1.2830x over previous
//
#include <hip/hip_runtime.h>
#include <stdint.h>

#define NN 50000
#define NE 800000
#define DN 64
#define DEIN 192
#define DM 128
#define CAP 64          // bucket capacity (Poisson(16); P(>=64) negligible)
#define EB 64           // edge/node rows per tile

#define SA_STR 216      // 432B row stride: 16B-aligned, 2-way bank alias (free)
#define SO_STR 136      // 272B: 16B-aligned
#define SX_STR 264      // 528B: 16B-aligned, 2-way alias

typedef __attribute__((ext_vector_type(4))) float f32x4;
typedef __attribute__((ext_vector_type(8))) short s16x8;

__device__ __forceinline__ unsigned short f2bf(float f) {
  union { float f; uint32_t u; } v; v.f = f;
  uint32_t u = v.u;
  u += 0x7FFF + ((u >> 16) & 1);   // RNE
  return (unsigned short)(u >> 16);
}
__device__ __forceinline__ float bf2f(unsigned short h) {
  union { uint32_t u; float f; } v; v.u = ((uint32_t)h) << 16;
  return v.f;
}
__device__ __forceinline__ ushort4 cvt4(float4 v) {
  ushort4 b; b.x = f2bf(v.x); b.y = f2bf(v.y); b.z = f2bf(v.z); b.w = f2bf(v.w);
  return b;
}

// ---- weight prep: bf16 transposed [n][k] layouts; reverse direction's
// column-swap folded into B1rT rows; W2f/W2r stacked into one K=256 matrix.
__global__ void kw2(const float* __restrict__ W1f, const float* __restrict__ W1r,
                    const float* __restrict__ W2f, const float* __restrict__ W2r,
                    const float* __restrict__ Wn1, const float* __restrict__ Wn2,
                    unsigned short* __restrict__ B1fT, unsigned short* __restrict__ B1rT,
                    unsigned short* __restrict__ B2T, unsigned short* __restrict__ Bn1T,
                    unsigned short* __restrict__ Bn2T) {
  int i = blockIdx.x * 256 + threadIdx.x;
  if (i < DM * DEIN) {
    int n = i / DEIN, k = i % DEIN;
    int pk = k < 64 ? k + 64 : (k < 128 ? k - 64 : k);
    B1fT[i] = f2bf(W1f[k * DM + n]);
    B1rT[i] = f2bf(W1r[pk * DM + n]);
    Bn1T[i] = f2bf(Wn1[k * DM + n]);
  }
  if (i < DM * 256) {
    int n = i / 256, k = i % 256;
    B2T[i] = f2bf(k < DM ? W2f[k * DM + n] : W2r[(k - DM) * DM + n]);
  }
  if (i < DN * DM) {
    int n = i / DM, k = i % DM;
    Bn2T[i] = f2bf(Wn2[k * DN + n]);
  }
}

// ---- bucket build
__global__ void kbucket(const int* __restrict__ tidx, const int* __restrict__ fidx,
                        int* __restrict__ cnt_to, int* __restrict__ cnt_from,
                        int* __restrict__ b_to, int* __restrict__ b_from) {
  int e = blockIdx.x * 256 + threadIdx.x;
  if (e >= NE) return;
  int t = tidx[e]; int s = atomicAdd(&cnt_to[t], 1);    if (s  < CAP) b_to[t * CAP + s]   = e;
  int f = fidx[e]; int s2 = atomicAdd(&cnt_from[f], 1); if (s2 < CAP) b_from[f * CAP + s2] = e;
}

// ---- fused edge kernel: both directions per staged tile.
// 1024 threads = 16 waves; wave = (dir = w>>3, nt = w&7); B frags in regs.
// Double-buffered sA, T14 split staging (issue loads -> MFMA -> cvt+ds_write).
__launch_bounds__(1024, 4)
__global__ void kedge2(const float* __restrict__ ns, const float* __restrict__ ef,
                       const int* __restrict__ fidx, const int* __restrict__ tidx,
                       const unsigned short* __restrict__ B1fT,
                       const unsigned short* __restrict__ B1rT,
                       const float* __restrict__ b1f, const float* __restrict__ b1r,
                       unsigned short* __restrict__ Hf, unsigned short* __restrict__ Hr,
                       int e_base, int e_count) {
  __shared__ __align__(16) unsigned short sA[2][EB][SA_STR];
  __shared__ __align__(16) unsigned short sO[2][EB][SO_STR];
  __shared__ float sb[2][DM];
  const int tid = threadIdx.x;
  const int w = tid >> 6, lane = tid & 63, g = lane >> 4, lr = lane & 15;
  const int dir = w >> 3, nt = w & 7;

  if (tid < 2 * DM) sb[tid >> 7][tid & 127] = (tid < DM ? b1f[tid] : b1r[tid - DM]);

  const unsigned short* BT = dir ? B1rT : B1fT;
  s16x8 bq[6];
#pragma unroll
  for (int kt = 0; kt < 6; kt++)
    bq[kt] = *(const s16x8*)&BT[(nt * 16 + lr) * DEIN + kt * 32 + g * 8];

  const int srow = tid >> 4, c4 = tid & 15;   // 16 threads per edge row
  const int ntiles = (e_count + EB - 1) / EB;

  float4 sv0, sv1, sv2;
  auto issue = [&](int tile) {
    int ei = tile * EB + srow;
    bool val = ei < e_count;
    int ec = val ? (e_base + ei) : e_base;
    int f = fidx[ec], t = tidx[ec];
    float4 z = {0.f, 0.f, 0.f, 0.f};
    sv0 = val ? *((const float4*)(ns + (size_t)f * DN) + c4) : z;
    sv1 = val ? *((const float4*)(ns + (size_t)t * DN) + c4) : z;
    sv2 = val ? *((const float4*)(ef + (size_t)ec * DN) + c4) : z;
  };
  auto store = [&](int buf) {
    *(ushort4*)&sA[buf][srow][0   + c4 * 4] = cvt4(sv0);
    *(ushort4*)&sA[buf][srow][64  + c4 * 4] = cvt4(sv1);
    *(ushort4*)&sA[buf][srow][128 + c4 * 4] = cvt4(sv2);
  };

  int cur = 0;
  issue(blockIdx.x);
  store(0);
  __syncthreads();
  for (int t = blockIdx.x; t < ntiles; t += gridDim.x) {
    int tn = t + (int)gridDim.x;
    bool hn = tn < ntiles;
    if (hn) issue(tn);                       // loads in flight during MFMA
    f32x4 acc[4];
#pragma unroll
    for (int m = 0; m < 4; m++) {
      s16x8 a[6];
#pragma unroll
      for (int kt = 0; kt < 6; kt++)
        a[kt] = *(const s16x8*)&sA[cur][m * 16 + lr][kt * 32 + g * 8];
      f32x4 c = {0.f, 0.f, 0.f, 0.f};
#pragma unroll
      for (int kt = 0; kt < 6; kt++)
        c = __builtin_amdgcn_mfma_f32_16x16x32_bf16(a[kt], bq[kt], c, 0, 0, 0);
      acc[m] = c;
    }
    if (hn) store(cur ^ 1);
    __syncthreads();
    // epilogue: relu+bias -> sO[dir] (bf16)
    float bb = sb[dir][nt * 16 + lr];
#pragma unroll
    for (int m = 0; m < 4; m++)
#pragma unroll
      for (int r = 0; r < 4; r++)
        sO[dir][m * 16 + g * 4 + r][nt * 16 + lr] = f2bf(fmaxf(acc[m][r] + bb, 0.f));
    __syncthreads();
    // coalesced copy-out of both H buffers
#pragma unroll
    for (int h = 0; h < 2; h++) {
      int c = tid + h * 1024;
      int d = c >> 10, rem = c & 1023, rr = rem >> 4, c8 = rem & 15;
      int ei = t * EB + rr;
      if (ei < e_count) {
        unsigned short* H = d ? Hr : Hf;
        *(int4*)&H[(size_t)ei * DM + c8 * 8] = *(const int4*)&sO[d][rr][c8 * 8];
      }
    }
    cur ^= 1;
  }
}

// ---- aggregation, both directions, 8-deep MLP (independent masked loads)
__global__ void kagg3(const unsigned short* __restrict__ Hf, const unsigned short* __restrict__ Hr,
                      const int* __restrict__ b_to, const int* __restrict__ b_from,
                      const int* __restrict__ cnt_to, const int* __restrict__ cnt_from,
                      float* __restrict__ agg, int e_base, int e_count) {
  int w = threadIdx.x >> 6, lane = threadIdx.x & 63;
  int n = blockIdx.x * 4 + w;
  if (n >= NN) return;
#pragma unroll
  for (int d = 0; d < 2; d++) {
    const unsigned short* H = d ? Hr : Hf;
    const int* bkt = (d ? b_from : b_to) + (size_t)n * CAP;
    int m = d ? cnt_from[n] : cnt_to[n]; if (m > CAP) m = CAP;
    int mye = bkt[lane];                 // lane j holds edge id j (coalesced 256B)
    float s0 = 0.f, s1 = 0.f;
    for (int j0 = 0; j0 < m; j0 += 8) {
      size_t off[8]; float mk[8]; uint32_t vv[8];
#pragma unroll
      for (int u = 0; u < 8; u++) {
        int ej = __shfl(mye, j0 + u);    // register broadcast, no memory chain
        unsigned er = (unsigned)(ej - e_base);
        bool ok = (j0 + u < m) && (er < (unsigned)e_count);
        off[u] = (size_t)(ok ? (int)er : 0) * DM + lane * 2;
        mk[u] = ok ? 1.f : 0.f;
      }
#pragma unroll
      for (int u = 0; u < 8; u++)        // 8 independent loads in flight
        vv[u] = *(const uint32_t*)&H[off[u]];
#pragma unroll
      for (int u = 0; u < 8; u++) {
        s0 = fmaf(mk[u], bf2f((unsigned short)(vv[u] & 0xFFFF)), s0);
        s1 = fmaf(mk[u], bf2f((unsigned short)(vv[u] >> 16)), s1);
      }
    }
    float* dst = agg + (size_t)n * 256 + d * DM + lane * 2;
    if (e_base == 0) { dst[0] = s0; dst[1] = s1; }
    else             { dst[0] += s0; dst[1] += s1; }
  }
}

// ---- second layer as MFMA GEMM: msg = [aggF|aggR] @ [W2f;W2r] + cntT*b2f + cntF*b2r
__launch_bounds__(256, 2)
__global__ void kmm3(const float* __restrict__ agg, const unsigned short* __restrict__ B2T,
                     const float* __restrict__ b2f, const float* __restrict__ b2r,
                     const int* __restrict__ cnt_to, const int* __restrict__ cnt_from,
                     unsigned short* __restrict__ msg) {
  __shared__ __align__(16) unsigned short sX[2][EB][SX_STR];
  __shared__ float sb[2][DM];
  const int tid = threadIdx.x;
  const int w = tid >> 6, lane = tid & 63, g = lane >> 4, lr = lane & 15;
  if (tid < 2 * DM) sb[tid >> 7][tid & 127] = tid < DM ? b2f[tid] : b2r[tid - DM];

  s16x8 bq[2][8];
#pragma unroll
  for (int p = 0; p < 2; p++)
#pragma unroll
    for (int kt = 0; kt < 8; kt++)
      bq[p][kt] = *(const s16x8*)&B2T[((2 * w + p) * 16 + lr) * 256 + kt * 32 + g * 8];

  const int ntiles = (NN + EB - 1) / EB;
  auto stage = [&](int buf, int tile) {
    for (int i = tid; i < EB * 64; i += 256) {
      int rr = i >> 6, q = i & 63;
      int node = tile * EB + rr; if (node >= NN) node = NN - 1;
      float4 v = *((const float4*)(agg + (size_t)node * 256) + q);
      *(ushort4*)&sX[buf][rr][q * 4] = cvt4(v);
    }
  };
  int cur = 0;
  stage(0, blockIdx.x);
  __syncthreads();
  for (int t = blockIdx.x; t < ntiles; t += gridDim.x) {
    int tn = t + (int)gridDim.x;
    bool hn = tn < ntiles;
    if (hn) stage(cur ^ 1, tn);
    f32x4 acc[4][2];
#pragma unroll
    for (int m = 0; m < 4; m++) {
      s16x8 a[8];
#pragma unroll
      for (int kt = 0; kt < 8; kt++)
        a[kt] = *(const s16x8*)&sX[cur][m * 16 + lr][kt * 32 + g * 8];
#pragma unroll
      for (int p = 0; p < 2; p++) {
        f32x4 c = {0.f, 0.f, 0.f, 0.f};
#pragma unroll
        for (int kt = 0; kt < 8; kt++)
          c = __builtin_amdgcn_mfma_f32_16x16x32_bf16(a[kt], bq[p][kt], c, 0, 0, 0);
        acc[m][p] = c;
      }
    }
    // epilogue (no LDS hazard: writes global only)
#pragma unroll
    for (int m = 0; m < 4; m++)
#pragma unroll
      for (int r = 0; r < 4; r++) {
        int node = t * EB + m * 16 + g * 4 + r;
        if (node < NN) {
          float cT = (float)cnt_to[node], cF = (float)cnt_from[node];
#pragma unroll
          for (int p = 0; p < 2; p++) {
            int cc = (2 * w + p) * 16 + lr;
            msg[(size_t)node * DM + cc] = f2bf(acc[m][p][r] + cT * sb[0][cc] + cF * sb[1][cc]);
          }
        }
      }
    __syncthreads();
    cur ^= 1;
  }
}

// ---- node MLP (two layers fused, MFMA) + residual
__launch_bounds__(256, 2)
__global__ void knode3(const unsigned short* __restrict__ msg, const float* __restrict__ ns,
                       const unsigned short* __restrict__ Bn1T, const unsigned short* __restrict__ Bn2T,
                       const float* __restrict__ bn1, const float* __restrict__ bn2,
                       float* __restrict__ out) {
  __shared__ __align__(16) unsigned short sX[2][EB][SA_STR];
  __shared__ __align__(16) unsigned short sH[EB][SO_STR];
  __shared__ float sb1[DM], sb2[DN];
  const int tid = threadIdx.x;
  const int w = tid >> 6, lane = tid & 63, g = lane >> 4, lr = lane & 15;
  if (tid < DM) sb1[tid] = bn1[tid];
  if (tid < DN) sb2[tid] = bn2[tid];

  s16x8 b1q[2][6], b2q[4];
#pragma unroll
  for (int p = 0; p < 2; p++)
#pragma unroll
    for (int kt = 0; kt < 6; kt++)
      b1q[p][kt] = *(const s16x8*)&Bn1T[((2 * w + p) * 16 + lr) * DEIN + kt * 32 + g * 8];
#pragma unroll
  for (int kt = 0; kt < 4; kt++)
    b2q[kt] = *(const s16x8*)&Bn2T[(w * 16 + lr) * DM + kt * 32 + g * 8];

  const int ntiles = (NN + EB - 1) / EB;
  auto stage = [&](int buf, int tile) {
    for (int i = tid; i < EB * 16; i += 256) {          // msg (bf16 direct copy)
      int rr = i >> 4, c8 = i & 15;
      int node = tile * EB + rr; if (node >= NN) node = NN - 1;
      *(int4*)&sX[buf][rr][c8 * 8] = *(const int4*)&msg[(size_t)node * DM + c8 * 8];
    }
    for (int i = tid; i < EB * 16; i += 256) {          // ns (f32 -> bf16)
      int rr = i >> 4, c4 = i & 15;
      int node = tile * EB + rr; if (node >= NN) node = NN - 1;
      float4 v = *((const float4*)(ns + (size_t)node * DN) + c4);
      *(ushort4*)&sX[buf][rr][DM + c4 * 4] = cvt4(v);
    }
  };
  int cur = 0;
  stage(0, blockIdx.x);
  __syncthreads();
  for (int t = blockIdx.x; t < ntiles; t += gridDim.x) {
    int tn = t + (int)gridDim.x;
    bool hn = tn < ntiles;
    if (hn) stage(cur ^ 1, tn);
    f32x4 acc1[4][2];
#pragma unroll
    for (int m = 0; m < 4; m++) {
      s16x8 a[6];
#pragma unroll
      for (int kt = 0; kt < 6; kt++)
        a[kt] = *(const s16x8*)&sX[cur][m * 16 + lr][kt * 32 + g * 8];
#pragma unroll
      for (int p = 0; p < 2; p++) {
        f32x4 c = {0.f, 0.f, 0.f, 0.f};
#pragma unroll
        for (int kt = 0; kt < 6; kt++)
          c = __builtin_amdgcn_mfma_f32_16x16x32_bf16(a[kt], b1q[p][kt], c, 0, 0, 0);
        acc1[m][p] = c;
      }
    }
    __syncthreads();
#pragma unroll
    for (int m = 0; m < 4; m++)
#pragma unroll
      for (int p = 0; p < 2; p++) {
        int cc = (2 * w + p) * 16 + lr;
#pragma unroll
        for (int r = 0; r < 4; r++)
          sH[m * 16 + g * 4 + r][cc] = f2bf(fmaxf(acc1[m][p][r] + sb1[cc], 0.f));
      }
    __syncthreads();
#pragma unroll
    for (int m = 0; m < 4; m++) {
      s16x8 a2[4];
#pragma unroll
      for (int kt = 0; kt < 4; kt++)
        a2[kt] = *(const s16x8*)&sH[m * 16 + lr][kt * 32 + g * 8];
      f32x4 c = {0.f, 0.f, 0.f, 0.f};
#pragma unroll
      for (int kt = 0; kt < 4; kt++)
        c = __builtin_amdgcn_mfma_f32_16x16x32_bf16(a2[kt], b2q[kt], c, 0, 0, 0);
      int col = w * 16 + lr;
#pragma unroll
      for (int r = 0; r < 4; r++) {
        int node = t * EB + m * 16 + g * 4 + r;
        if (node < NN)
          out[(size_t)node * DN + col] = ns[(size_t)node * DN + col] + c[r] + sb2[col];
      }
    }
    __syncthreads();
    cur ^= 1;
  }
}

extern "C" void kernel_launch(void* const* d_in, const int* in_sizes, int n_in,
                              void* d_out, int out_size, void* d_ws, size_t ws_size,
                              hipStream_t stream) {
  const float* ns  = (const float*)d_in[0];
  const float* ef  = (const float*)d_in[1];
  const float* W1f = (const float*)d_in[2];
  const float* b1f = (const float*)d_in[3];
  const float* W2f = (const float*)d_in[4];
  const float* b2f = (const float*)d_in[5];
  const float* W1r = (const float*)d_in[6];
  const float* b1r = (const float*)d_in[7];
  const float* W2r = (const float*)d_in[8];
  const float* b2r = (const float*)d_in[9];
  const float* Wn1 = (const float*)d_in[10];
  const float* bn1 = (const float*)d_in[11];
  const float* Wn2 = (const float*)d_in[12];
  const float* bn2 = (const float*)d_in[13];
  const int* fidx  = (const int*)d_in[14];
  const int* tidx  = (const int*)d_in[15];
  float* out = (float*)d_out;

  char* ws = (char*)d_ws;
  size_t off = 0;
  auto alloc = [&](size_t bytes) {
    off = (off + 255) & ~(size_t)255;
    void* p = ws + off; off += bytes; return p;
  };
  float* agg            = (float*)alloc((size_t)NN * 256 * 4);
  unsigned short* msg   = (unsigned short*)alloc((size_t)NN * DM * 2);
  int* b_to             = (int*)alloc((size_t)NN * CAP * 4);
  int* b_from           = (int*)alloc((size_t)NN * CAP * 4);
  int* cnt_to           = (int*)alloc((size_t)NN * 4);
  int* cnt_from         = (int*)alloc((size_t)NN * 4);
  unsigned short* B1fT  = (unsigned short*)alloc((size_t)DM * DEIN * 2);
  unsigned short* B1rT  = (unsigned short*)alloc((size_t)DM * DEIN * 2);
  unsigned short* B2T   = (unsigned short*)alloc((size_t)DM * 256 * 2);
  unsigned short* Bn1T  = (unsigned short*)alloc((size_t)DM * DEIN * 2);
  unsigned short* Bn2T  = (unsigned short*)alloc((size_t)DN * DM * 2);
  off = (off + 255) & ~(size_t)255;
  size_t rem = ws_size > off ? ws_size - off : 0;
  size_t chunk_sz = rem / (DM * 2 * 2);     // Hf + Hr per edge
  int chunk = chunk_sz > (size_t)NE ? NE : (int)chunk_sz;
  chunk &= ~(EB - 1);
  if (chunk < EB) return;
  unsigned short* Hf = (unsigned short*)alloc((size_t)chunk * DM * 2);
  unsigned short* Hr = (unsigned short*)alloc((size_t)chunk * DM * 2);

  hipMemsetAsync(cnt_to, 0, (size_t)NN * 4, stream);
  hipMemsetAsync(cnt_from, 0, (size_t)NN * 4, stream);
  kw2<<<128, 256, 0, stream>>>(W1f, W1r, W2f, W2r, Wn1, Wn2, B1fT, B1rT, B2T, Bn1T, Bn2T);
  kbucket<<<(NE + 255) / 256, 256, 0, stream>>>(tidx, fidx, cnt_to, cnt_from, b_to, b_from);

  for (int c0 = 0; c0 < NE; c0 += chunk) {
    int cc = (NE - c0) < chunk ? (NE - c0) : chunk;
    int ntiles = (cc + EB - 1) / EB;
    int grid = ntiles < 512 ? ntiles : 512;
    kedge2<<<grid, 1024, 0, stream>>>(ns, ef, fidx, tidx, B1fT, B1rT, b1f, b1r, Hf, Hr, c0, cc);
    kagg3<<<(NN + 3) / 4, 256, 0, stream>>>(Hf, Hr, b_to, b_from, cnt_to, cnt_from, agg, c0, cc);
  }
  int ntiles_n = (NN + EB - 1) / EB;
  int gridn = ntiles_n < 512 ? ntiles_n : 512;
  kmm3<<<gridn, 256, 0, stream>>>(agg, B2T, b2f, b2r, cnt_to, cnt_from, msg);
  knode3<<<gridn, 256, 0, stream>>>(msg, ns, Bn1T, Bn2T, bn1, bn2, out);
}